// Round 3
// baseline (1082.777 us; speedup 1.0000x reference)
//
#include <hip/hip_runtime.h>

#define N_NODES 100000
#define N_EDGES 3200000
#define F_IN 128
#define F_OUT 32
#define N_GRAPHS 64

#define NB 2048                 // dst buckets
#define BN 49                   // nodes per bucket: 2048*49 = 100352 >= N_NODES
#define NSLICE 8                // writer slices per bucket (XCD line locality)
#define NCNT (NB * NSLICE)      // 16384 cursors
#define HGRID 2048              // hist/scatter grid — MUST match between the two

// ---------------------------------------------------------------------------
// Node transforms xl = x@W_l + b_l ; xr = x@W_r + b_r.
// Wl/Wr interleaved as float2 in LDS: one ds_read_b64 per k instead of two
// b32 (lanes f,f+16 share a bank pair -> 2-way = free).
// ---------------------------------------------------------------------------
__global__ __launch_bounds__(256) void gat_transform(
    const float* __restrict__ x,
    const float* __restrict__ Wl, const float* __restrict__ bl,
    const float* __restrict__ Wr, const float* __restrict__ br,
    float* __restrict__ xl, float* __restrict__ xr)
{
    __shared__ float2 sW[F_IN * F_OUT];
    for (int i = threadIdx.x; i < F_IN * F_OUT; i += 256)
        sW[i] = make_float2(Wl[i], Wr[i]);
    __syncthreads();

    const int f    = threadIdx.x & 31;
    const int node = blockIdx.x * 8 + (threadIdx.x >> 5);
    if (node >= N_NODES) return;

    const float4* xrow = (const float4*)(x + (size_t)node * F_IN);
    float accl = bl[f];
    float accr = br[f];
#pragma unroll
    for (int k4 = 0; k4 < F_IN / 4; ++k4) {
        float4 v = xrow[k4];
        const int k = k4 * 4;
        float2 w0 = sW[(k + 0) * 32 + f]; accl += v.x * w0.x; accr += v.x * w0.y;
        float2 w1 = sW[(k + 1) * 32 + f]; accl += v.y * w1.x; accr += v.y * w1.y;
        float2 w2 = sW[(k + 2) * 32 + f]; accl += v.z * w2.x; accr += v.z * w2.y;
        float2 w3 = sW[(k + 3) * 32 + f]; accl += v.w * w3.x; accr += v.w * w3.y;
    }
    xl[(size_t)node * 32 + f] = accl;
    xr[(size_t)node * 32 + f] = accr;
}

// ---------------------------------------------------------------------------
// Bucket histogram: count edges per (bucket, writer-slice). Slice is a
// function of blockIdx so hist and scatter assign edges identically.
// ---------------------------------------------------------------------------
__global__ __launch_bounds__(256) void bkt_hist(const int* __restrict__ ei,
                                                int* __restrict__ cnt)
{
    const int slice  = blockIdx.x & (NSLICE - 1);
    const int stride = gridDim.x * blockDim.x;
    for (int e = blockIdx.x * blockDim.x + threadIdx.x; e < N_EDGES; e += stride) {
        const int dst = ei[N_EDGES + e];
        atomicAdd(&cnt[(dst / BN) * NSLICE + slice], 1);
    }
}

// ---------------------------------------------------------------------------
// Exclusive scan of 16384 counters (single block). Writes base[] (kept) and
// cursor[] (consumed by scatter). base[NCNT] = N_EDGES sentinel.
// ---------------------------------------------------------------------------
__global__ __launch_bounds__(256) void bkt_scan(const int* __restrict__ cnt,
                                                int* __restrict__ base,
                                                int* __restrict__ cursor)
{
    __shared__ int s[256];
    const int t = threadIdx.x;
    const int R = NCNT / 256;   // 64
    int sum = 0;
    for (int r = 0; r < R; ++r) sum += cnt[t * R + r];
    s[t] = sum;
    __syncthreads();
    for (int off = 1; off < 256; off <<= 1) {
        int u = (t >= off) ? s[t - off] : 0;
        __syncthreads();
        s[t] += u;
        __syncthreads();
    }
    int run = s[t] - sum;   // exclusive base for this thread's range
    for (int r = 0; r < R; ++r) {
        const int i = t * R + r;
        const int c = cnt[i];
        base[i] = run;
        cursor[i] = run;
        run += c;
    }
    if (t == 255) base[NCNT] = run;   // == N_EDGES
}

// ---------------------------------------------------------------------------
// Bucketed scatter: pack {src | dst_local<<17, edge_attr} into the bucket's
// region. 16K active cursors -> ~1MB active write lines -> full-line
// writebacks (vs 199MB of partial-line waste in the full CSR scatter).
// ---------------------------------------------------------------------------
__global__ __launch_bounds__(256) void bkt_scatter(const int* __restrict__ ei,
                                                   const float* __restrict__ eattr,
                                                   int* __restrict__ cursor,
                                                   int2* __restrict__ es2)
{
    const int slice  = blockIdx.x & (NSLICE - 1);
    const int stride = gridDim.x * blockDim.x;
    for (int e = blockIdx.x * blockDim.x + threadIdx.x; e < N_EDGES; e += stride) {
        const int src = ei[e];
        const int dst = ei[N_EDGES + e];
        const int b   = dst / BN;
        const int dl  = dst - b * BN;           // 0..48 (6 bits)
        const int pos = atomicAdd(&cursor[b * NSLICE + slice], 1);
        es2[pos] = make_int2(src | (dl << 17), __float_as_int(eattr[e]));
    }
}

// ---------------------------------------------------------------------------
// Aggregate: one block per bucket. xr slice + accumulators live in LDS;
// 8 edge-groups × 4-deep batched gathers; LDS atomics (no global atomics).
// h output aliases xr (block reads its own slice first, then overwrites).
// ---------------------------------------------------------------------------
#define PROCESS(e, xv) do {                                                   \
    const int dl_ = (e).x >> 17;                                              \
    float m_ = (xv) + sxr[dl_ * 32 + f] + __int_as_float((e).y) * wef;        \
    m_ = (m_ > 0.f) ? m_ : 0.2f * m_;                                         \
    float t_ = m_ * attf;                                                     \
    t_ += __shfl_xor(t_, 16, 32);                                             \
    t_ += __shfl_xor(t_, 8, 32);                                              \
    t_ += __shfl_xor(t_, 4, 32);                                              \
    t_ += __shfl_xor(t_, 2, 32);                                              \
    t_ += __shfl_xor(t_, 1, 32);                                              \
    const float p_ = __expf(t_);                                              \
    atomicAdd(&sacc[dl_ * 32 + f], (xv) * p_);                                \
    if (f == 0) atomicAdd(&sden[dl_], p_);                                    \
} while (0)

__global__ __launch_bounds__(256) void gat_aggregate(
    const int2* __restrict__ es2, const int* __restrict__ base,
    const float* __restrict__ We, const float* __restrict__ att,
    const float* __restrict__ xl, float* xrh)
{
    __shared__ float sxr[BN * 32];
    __shared__ float sacc[BN * 32];
    __shared__ float sden[BN];

    const int b    = blockIdx.x;
    const int n0   = b * BN;
    const int n1   = (n0 + BN < N_NODES) ? (n0 + BN) : N_NODES;
    const int nrow = n1 - n0;
    const int tid  = threadIdx.x;

    if (nrow > 0) {
        for (int i = tid; i < nrow * 32; i += 256) {
            sxr[i]  = xrh[(size_t)n0 * 32 + i];
            sacc[i] = 0.f;
        }
        for (int i = tid; i < nrow; i += 256) sden[i] = 0.f;
    }
    __syncthreads();
    if (nrow <= 0) return;

    const int f = tid & 31;
    const int g = tid >> 5;
    const float attf = att[f];
    const float wef  = We[f];

    const int beg = base[b * NSLICE];
    const int end = base[(b + 1) * NSLICE];

    int j0 = beg;
    for (; j0 + 32 <= end; j0 += 32) {
        int2 e0 = es2[j0 + g];
        int2 e1 = es2[j0 + g + 8];
        int2 e2 = es2[j0 + g + 16];
        int2 e3 = es2[j0 + g + 24];
        float x0 = xl[(size_t)(e0.x & 0x1FFFF) * 32 + f];
        float x1 = xl[(size_t)(e1.x & 0x1FFFF) * 32 + f];
        float x2 = xl[(size_t)(e2.x & 0x1FFFF) * 32 + f];
        float x3 = xl[(size_t)(e3.x & 0x1FFFF) * 32 + f];
        PROCESS(e0, x0);
        PROCESS(e1, x1);
        PROCESS(e2, x2);
        PROCESS(e3, x3);
    }
    for (int j = j0 + g; j < end; j += 8) {
        int2 e = es2[j];
        float xv = xl[(size_t)(e.x & 0x1FFFF) * 32 + f];
        PROCESS(e, xv);
    }
    __syncthreads();

    for (int i = tid; i < nrow * 32; i += 256)
        xrh[(size_t)n0 * 32 + i] = sacc[i] / (sden[i >> 5] + 1e-16f);
}

// ---------------------------------------------------------------------------
// Pool: mean over each graph's node range (batch sorted), + bias.
// ---------------------------------------------------------------------------
__global__ __launch_bounds__(256) void gat_pool(
    const float* __restrict__ h, const float* __restrict__ bias,
    const int* __restrict__ batch, float* __restrict__ out)
{
    const int g = blockIdx.x;
    __shared__ int s_lo, s_hi;
    if (threadIdx.x == 0) {
        int lo = 0, hi = N_NODES;
        while (lo < hi) { int mid = (lo + hi) >> 1; if (batch[mid] < g) lo = mid + 1; else hi = mid; }
        s_lo = lo;
        lo = 0; hi = N_NODES;
        while (lo < hi) { int mid = (lo + hi) >> 1; if (batch[mid] < g + 1) lo = mid + 1; else hi = mid; }
        s_hi = lo;
    }
    __syncthreads();
    const int lo = s_lo, hi = s_hi;

    const int f   = threadIdx.x & 31;
    const int grp = threadIdx.x >> 5;

    float acc = 0.f;
    for (int n = lo + grp; n < hi; n += 8)
        acc += h[(size_t)n * 32 + f];

    __shared__ float s_acc[8][32];
    s_acc[grp][f] = acc;
    __syncthreads();

    if (threadIdx.x < 32) {
        float sum = 0.f;
#pragma unroll
        for (int i = 0; i < 8; ++i) sum += s_acc[i][f];
        const int cnt = hi - lo;
        out[g * 32 + f] = (cnt > 0) ? (sum / (float)cnt + bias[f]) : 0.f;
    }
}

// ---------------------------------------------------------------------------
extern "C" void kernel_launch(void* const* d_in, const int* in_sizes, int n_in,
                              void* d_out, int out_size, void* d_ws, size_t ws_size,
                              hipStream_t stream)
{
    const float* x     = (const float*)d_in[0];
    const float* eattr = (const float*)d_in[1];
    const float* Wl    = (const float*)d_in[2];
    const float* bl    = (const float*)d_in[3];
    const float* Wr    = (const float*)d_in[4];
    const float* br    = (const float*)d_in[5];
    const float* We    = (const float*)d_in[6];
    const float* att   = (const float*)d_in[7];
    const float* bias  = (const float*)d_in[8];
    const int*   ei    = (const int*)d_in[9];
    const int*   batch = (const int*)d_in[10];
    float* out = (float*)d_out;

    float* ws = (float*)d_ws;
    const size_t NF = (size_t)N_NODES * 32;

    float* xl     = ws;                        // [N_NODES*32]
    float* xrh    = ws + NF;                   // [N_NODES*32]  (xr, then h)
    int2*  es2    = (int2*)(ws + 2 * NF);      // [N_EDGES]
    int*   cnt    = (int*)(es2 + N_EDGES);     // [NCNT]
    int*   base   = cnt + NCNT;                // [NCNT+1]
    int*   cursor = base + NCNT + 1;           // [NCNT]

    hipMemsetAsync(cnt, 0, NCNT * sizeof(int), stream);

    bkt_hist<<<HGRID, 256, 0, stream>>>(ei, cnt);
    bkt_scan<<<1, 256, 0, stream>>>(cnt, base, cursor);
    bkt_scatter<<<HGRID, 256, 0, stream>>>(ei, eattr, cursor, es2);

    gat_transform<<<(N_NODES + 7) / 8, 256, 0, stream>>>(x, Wl, bl, Wr, br, xl, xrh);
    gat_aggregate<<<NB, 256, 0, stream>>>(es2, base, We, att, xl, xrh);
    gat_pool<<<N_GRAPHS, 256, 0, stream>>>(xrh, bias, batch, out);
}

// Round 4
// 963.462 us; speedup vs baseline: 1.1238x; 1.1238x over previous
//
#include <hip/hip_runtime.h>

#define N_NODES 100000
#define N_EDGES 3200000
#define F_IN 128
#define F_OUT 32
#define N_GRAPHS 64

#define NB 1024                    // dst buckets
#define BN2 98                     // nodes per bucket: 1024*98 = 100352 >= N
#define HGRID 128                  // hist/scatter blocks (chunk owners)
#define CHUNK (N_EDGES / HGRID)    // 25000 edges per chunk, exact
#define NCUR (NB * HGRID)          // 131072 cursors, bucket-major

// ---------------------------------------------------------------------------
// Transform: xl = x@W_l + b_l ; xr = x@W_r + b_r.
// 8 groups x 4 nodes per 256-block => each W LDS read feeds 4 nodes (DS /4).
// 100000 = 3125 * 32 exactly -> no tail guards.
// ---------------------------------------------------------------------------
__global__ __launch_bounds__(256) void gat_transform(
    const float* __restrict__ x,
    const float* __restrict__ Wl, const float* __restrict__ bl,
    const float* __restrict__ Wr, const float* __restrict__ br,
    float* __restrict__ xl, float* __restrict__ xr)
{
    __shared__ float2 sW[F_IN * F_OUT];   // (Wl, Wr) interleaved, [k][f]
    for (int i = threadIdx.x; i < F_IN * F_OUT; i += 256)
        sW[i] = make_float2(Wl[i], Wr[i]);
    __syncthreads();

    const int f     = threadIdx.x & 31;
    const int node0 = blockIdx.x * 32 + (threadIdx.x >> 5) * 4;

    const float4* x0 = (const float4*)(x + (size_t)(node0 + 0) * F_IN);
    const float4* x1 = (const float4*)(x + (size_t)(node0 + 1) * F_IN);
    const float4* x2 = (const float4*)(x + (size_t)(node0 + 2) * F_IN);
    const float4* x3 = (const float4*)(x + (size_t)(node0 + 3) * F_IN);

    const float bl_f = bl[f], br_f = br[f];
    float a0 = bl_f, a1 = bl_f, a2 = bl_f, a3 = bl_f;
    float r0 = br_f, r1 = br_f, r2 = br_f, r3 = br_f;

#pragma unroll 4
    for (int k4 = 0; k4 < F_IN / 4; ++k4) {
        float4 v0 = x0[k4], v1 = x1[k4], v2 = x2[k4], v3 = x3[k4];
        float2 w0 = sW[(4 * k4 + 0) * 32 + f];
        float2 w1 = sW[(4 * k4 + 1) * 32 + f];
        float2 w2 = sW[(4 * k4 + 2) * 32 + f];
        float2 w3 = sW[(4 * k4 + 3) * 32 + f];
        a0 += v0.x * w0.x + v0.y * w1.x + v0.z * w2.x + v0.w * w3.x;
        r0 += v0.x * w0.y + v0.y * w1.y + v0.z * w2.y + v0.w * w3.y;
        a1 += v1.x * w0.x + v1.y * w1.x + v1.z * w2.x + v1.w * w3.x;
        r1 += v1.x * w0.y + v1.y * w1.y + v1.z * w2.y + v1.w * w3.y;
        a2 += v2.x * w0.x + v2.y * w1.x + v2.z * w2.x + v2.w * w3.x;
        r2 += v2.x * w0.y + v2.y * w1.y + v2.z * w2.y + v2.w * w3.y;
        a3 += v3.x * w0.x + v3.y * w1.x + v3.z * w2.x + v3.w * w3.x;
        r3 += v3.x * w0.y + v3.y * w1.y + v3.z * w2.y + v3.w * w3.y;
    }
    xl[(size_t)(node0 + 0) * 32 + f] = a0;
    xl[(size_t)(node0 + 1) * 32 + f] = a1;
    xl[(size_t)(node0 + 2) * 32 + f] = a2;
    xl[(size_t)(node0 + 3) * 32 + f] = a3;
    xr[(size_t)(node0 + 0) * 32 + f] = r0;
    xr[(size_t)(node0 + 1) * 32 + f] = r1;
    xr[(size_t)(node0 + 2) * 32 + f] = r2;
    xr[(size_t)(node0 + 3) * 32 + f] = r3;
}

// ---------------------------------------------------------------------------
// Logit: one LANE per edge. Full 32-f dot in registers via float4 reads of
// xl[src], xr[dst] (rows are L1-resident within a wave's working set).
// No shfl, no atomics, no LDS. p[e] = exp(logit) written coalesced.
// ---------------------------------------------------------------------------
__global__ __launch_bounds__(256) void edge_logit(
    const int* __restrict__ ei, const float* __restrict__ eattr,
    const float* __restrict__ We, const float* __restrict__ att,
    const float* __restrict__ xl, const float* __restrict__ xr,
    float* __restrict__ p)
{
    const int e = blockIdx.x * 256 + threadIdx.x;
    if (e >= N_EDGES) return;

    const int   src = ei[e];
    const int   dst = ei[N_EDGES + e];
    const float ea  = eattr[e];

    const float4* xls = (const float4*)(xl + (size_t)src * 32);
    const float4* xrs = (const float4*)(xr + (size_t)dst * 32);
    const float4* We4  = (const float4*)We;
    const float4* att4 = (const float4*)att;

    float t = 0.f;
#pragma unroll
    for (int q = 0; q < 8; ++q) {
        const float4 a = xls[q];
        const float4 b = xrs[q];
        const float4 w = We4[q];     // wave-uniform broadcast (L1)
        const float4 v = att4[q];
        float m;
        m = a.x + b.x + ea * w.x; m = (m > 0.f) ? m : 0.2f * m; t += m * v.x;
        m = a.y + b.y + ea * w.y; m = (m > 0.f) ? m : 0.2f * m; t += m * v.y;
        m = a.z + b.z + ea * w.z; m = (m > 0.f) ? m : 0.2f * m; t += m * v.z;
        m = a.w + b.w + ea * w.w; m = (m > 0.f) ? m : 0.2f * m; t += m * v.w;
    }
    p[e] = __expf(t);
}

// ---------------------------------------------------------------------------
// Counting sort by dst-bucket, single-writer regions: cursor (b, c) is
// written only by chunk-block c -> sequential full-line region writes.
// ---------------------------------------------------------------------------
__global__ __launch_bounds__(256) void bkt_hist(const int* __restrict__ ei,
                                                int* __restrict__ cnt)
{
    __shared__ int hloc[NB];
    for (int i = threadIdx.x; i < NB; i += 256) hloc[i] = 0;
    __syncthreads();
    const int c  = blockIdx.x;
    const int e0 = c * CHUNK;
    for (int i = threadIdx.x; i < CHUNK; i += 256)
        atomicAdd(&hloc[ei[N_EDGES + e0 + i] / BN2], 1);
    __syncthreads();
    for (int b = threadIdx.x; b < NB; b += 256)
        cnt[b * HGRID + c] = hloc[b];
}

__global__ __launch_bounds__(1024) void bkt_scan(const int* __restrict__ cnt,
                                                 int* __restrict__ base)
{
    __shared__ int s[1024];
    const int t = threadIdx.x;            // bucket id
    const int* row = cnt + t * HGRID;
    int sum = 0;
#pragma unroll 4
    for (int i = 0; i < HGRID; ++i) sum += row[i];
    s[t] = sum;
    __syncthreads();
    for (int off = 1; off < 1024; off <<= 1) {
        const int u = (t >= off) ? s[t - off] : 0;
        __syncthreads();
        s[t] += u;
        __syncthreads();
    }
    int run = s[t] - sum;                 // exclusive bucket base
    int* brow = base + t * HGRID;
#pragma unroll 4
    for (int i = 0; i < HGRID; ++i) { brow[i] = run; run += row[i]; }
    if (t == 1023) base[NCUR] = run;      // sentinel == N_EDGES
}

__global__ __launch_bounds__(256) void bkt_scatter(const int* __restrict__ ei,
                                                   const float* __restrict__ p,
                                                   const int* __restrict__ base,
                                                   int2* __restrict__ es2)
{
    __shared__ int cur[NB];
    const int c = blockIdx.x;
    for (int b = threadIdx.x; b < NB; b += 256) cur[b] = base[b * HGRID + c];
    __syncthreads();
    const int e0 = c * CHUNK;
    for (int i = threadIdx.x; i < CHUNK; i += 256) {
        const int e   = e0 + i;
        const int src = ei[e];
        const int dst = ei[N_EDGES + e];
        const int b   = dst / BN2;
        const int dl  = dst - b * BN2;    // 0..97 (7 bits); src < 2^17
        const int pos = atomicAdd(&cur[b], 1);
        es2[pos] = make_int2(src | (dl << 17), __float_as_int(p[e]));
    }
}

// ---------------------------------------------------------------------------
// Aggregate: block per bucket. Per edge: uniform 8B read + xl row gather +
// ds_add_f32 (unsafeAtomicAdd). No shfl, no exp, no xr. h overwrites xr buf.
// ---------------------------------------------------------------------------
__global__ __launch_bounds__(256) void gat_aggregate(
    const int2* __restrict__ es2, const int* __restrict__ base,
    const float* __restrict__ xl, float* __restrict__ h)
{
    __shared__ float sacc[BN2 * 32];
    __shared__ float sden[BN2];
    const int b  = blockIdx.x;
    const int n0 = b * BN2;
    const int nrow = (N_NODES - n0 < BN2) ? (N_NODES - n0) : BN2;
    if (nrow <= 0) return;                 // uniform over block
    const int tid = threadIdx.x;
    for (int i = tid; i < nrow * 32; i += 256) sacc[i] = 0.f;
    for (int i = tid; i < nrow; i += 256)      sden[i] = 0.f;
    __syncthreads();

    const int f = tid & 31;
    const int g = tid >> 5;
    const int beg = base[b * HGRID];
    const int end = base[(b + 1) * HGRID];

    for (int j0 = beg; j0 < end; j0 += 16) {
        const int j = j0 + 2 * g;
        if (j < end) {
            const int2 e = es2[j];
            const float pv  = __int_as_float(e.y);
            const float xlv = xl[(size_t)(e.x & 0x1FFFF) * 32 + f];
            const int   dl  = e.x >> 17;
            unsafeAtomicAdd(&sacc[dl * 32 + f], xlv * pv);
            if (f == 0) unsafeAtomicAdd(&sden[dl], pv);
        }
        const int j2 = j + 1;
        if (j2 < end && (2 * g + 1) < 16) {
            const int2 e = es2[j2];
            const float pv  = __int_as_float(e.y);
            const float xlv = xl[(size_t)(e.x & 0x1FFFF) * 32 + f];
            const int   dl  = e.x >> 17;
            unsafeAtomicAdd(&sacc[dl * 32 + f], xlv * pv);
            if (f == 0) unsafeAtomicAdd(&sden[dl], pv);
        }
    }
    __syncthreads();

    for (int i = tid; i < nrow * 32; i += 256)
        h[(size_t)n0 * 32 + i] = sacc[i] / (sden[i >> 5] + 1e-16f);
}

// ---------------------------------------------------------------------------
// Pool: mean over each graph's node range (batch sorted), + bias.
// ---------------------------------------------------------------------------
__global__ __launch_bounds__(256) void gat_pool(
    const float* __restrict__ h, const float* __restrict__ bias,
    const int* __restrict__ batch, float* __restrict__ out)
{
    const int g = blockIdx.x;
    __shared__ int s_lo, s_hi;
    if (threadIdx.x == 0) {
        int lo = 0, hi = N_NODES;
        while (lo < hi) { int mid = (lo + hi) >> 1; if (batch[mid] < g) lo = mid + 1; else hi = mid; }
        s_lo = lo;
        lo = 0; hi = N_NODES;
        while (lo < hi) { int mid = (lo + hi) >> 1; if (batch[mid] < g + 1) lo = mid + 1; else hi = mid; }
        s_hi = lo;
    }
    __syncthreads();
    const int lo = s_lo, hi = s_hi;

    const int f   = threadIdx.x & 31;
    const int grp = threadIdx.x >> 5;

    float acc = 0.f;
    for (int n = lo + grp; n < hi; n += 8)
        acc += h[(size_t)n * 32 + f];

    __shared__ float s_acc[8][32];
    s_acc[grp][f] = acc;
    __syncthreads();

    if (threadIdx.x < 32) {
        float sum = 0.f;
#pragma unroll
        for (int i = 0; i < 8; ++i) sum += s_acc[i][f];
        const int cnt = hi - lo;
        out[g * 32 + f] = (cnt > 0) ? (sum / (float)cnt + bias[f]) : 0.f;
    }
}

// ---------------------------------------------------------------------------
extern "C" void kernel_launch(void* const* d_in, const int* in_sizes, int n_in,
                              void* d_out, int out_size, void* d_ws, size_t ws_size,
                              hipStream_t stream)
{
    const float* x     = (const float*)d_in[0];
    const float* eattr = (const float*)d_in[1];
    const float* Wl    = (const float*)d_in[2];
    const float* bl    = (const float*)d_in[3];
    const float* Wr    = (const float*)d_in[4];
    const float* br    = (const float*)d_in[5];
    const float* We    = (const float*)d_in[6];
    const float* att   = (const float*)d_in[7];
    const float* bias  = (const float*)d_in[8];
    const int*   ei    = (const int*)d_in[9];
    const int*   batch = (const int*)d_in[10];
    float* out = (float*)d_out;

    float* ws = (float*)d_ws;
    const size_t NF = (size_t)N_NODES * 32;

    float* xl   = ws;                       // [NF]
    float* xrh  = ws + NF;                  // [NF]  xr, then h
    float* p    = ws + 2 * NF;              // [N_EDGES]
    int2*  es2  = (int2*)(p + N_EDGES);     // [N_EDGES]
    int*   cnt  = (int*)(es2 + N_EDGES);    // [NCUR]
    int*   base = cnt + NCUR;               // [NCUR + 1]

    gat_transform<<<N_NODES / 32, 256, 0, stream>>>(x, Wl, bl, Wr, br, xl, xrh);
    bkt_hist<<<HGRID, 256, 0, stream>>>(ei, cnt);
    bkt_scan<<<1, 1024, 0, stream>>>(cnt, base);
    edge_logit<<<N_EDGES / 256, 256, 0, stream>>>(ei, eattr, We, att, xl, xrh, p);
    bkt_scatter<<<HGRID, 256, 0, stream>>>(ei, p, base, es2);
    gat_aggregate<<<NB, 256, 0, stream>>>(es2, base, xl, xrh);
    gat_pool<<<N_GRAPHS, 256, 0, stream>>>(xrh, bias, batch, out);
}

// Round 5
// 946.736 us; speedup vs baseline: 1.1437x; 1.0177x over previous
//
#include <hip/hip_runtime.h>

#define N_NODES 100000
#define N_EDGES 3200000
#define F_IN 128
#define F_OUT 32
#define N_GRAPHS 64

#define NBK 4096                   // dst buckets
#define BNK 25                     // nodes/bucket: 4096*25 = 102400 >= N; 3999*25+25 = 100000 exact
#define PAD 36                     // LDS row pad: (dl*36+f)%32 covers all banks
#define HG  128                    // chunk blocks for hist/scatter
#define CHUNK (N_EDGES / HG)       // 25000, exact
#define NCUR (NBK * HG)            // 524288 cursors

// ---------------------------------------------------------------------------
// Transform: xl = x@W_l + b_l ; xr = x@W_r + b_r. 4 nodes per 32-lane group.
// ---------------------------------------------------------------------------
__global__ __launch_bounds__(256) void gat_transform(
    const float* __restrict__ x,
    const float* __restrict__ Wl, const float* __restrict__ bl,
    const float* __restrict__ Wr, const float* __restrict__ br,
    float* __restrict__ xl, float* __restrict__ xr)
{
    __shared__ float2 sW[F_IN * F_OUT];
    for (int i = threadIdx.x; i < F_IN * F_OUT; i += 256)
        sW[i] = make_float2(Wl[i], Wr[i]);
    __syncthreads();

    const int f     = threadIdx.x & 31;
    const int node0 = blockIdx.x * 32 + (threadIdx.x >> 5) * 4;

    const float4* x0 = (const float4*)(x + (size_t)(node0 + 0) * F_IN);
    const float4* x1 = (const float4*)(x + (size_t)(node0 + 1) * F_IN);
    const float4* x2 = (const float4*)(x + (size_t)(node0 + 2) * F_IN);
    const float4* x3 = (const float4*)(x + (size_t)(node0 + 3) * F_IN);

    const float bl_f = bl[f], br_f = br[f];
    float a0 = bl_f, a1 = bl_f, a2 = bl_f, a3 = bl_f;
    float r0 = br_f, r1 = br_f, r2 = br_f, r3 = br_f;

#pragma unroll 4
    for (int k4 = 0; k4 < F_IN / 4; ++k4) {
        float4 v0 = x0[k4], v1 = x1[k4], v2 = x2[k4], v3 = x3[k4];
        float2 w0 = sW[(4 * k4 + 0) * 32 + f];
        float2 w1 = sW[(4 * k4 + 1) * 32 + f];
        float2 w2 = sW[(4 * k4 + 2) * 32 + f];
        float2 w3 = sW[(4 * k4 + 3) * 32 + f];
        a0 += v0.x * w0.x + v0.y * w1.x + v0.z * w2.x + v0.w * w3.x;
        r0 += v0.x * w0.y + v0.y * w1.y + v0.z * w2.y + v0.w * w3.y;
        a1 += v1.x * w0.x + v1.y * w1.x + v1.z * w2.x + v1.w * w3.x;
        r1 += v1.x * w0.y + v1.y * w1.y + v1.z * w2.y + v1.w * w3.y;
        a2 += v2.x * w0.x + v2.y * w1.x + v2.z * w2.x + v2.w * w3.x;
        r2 += v2.x * w0.y + v2.y * w1.y + v2.z * w2.y + v2.w * w3.y;
        a3 += v3.x * w0.x + v3.y * w1.x + v3.z * w2.x + v3.w * w3.x;
        r3 += v3.x * w0.y + v3.y * w1.y + v3.z * w2.y + v3.w * w3.y;
    }
    xl[(size_t)(node0 + 0) * 32 + f] = a0;
    xl[(size_t)(node0 + 1) * 32 + f] = a1;
    xl[(size_t)(node0 + 2) * 32 + f] = a2;
    xl[(size_t)(node0 + 3) * 32 + f] = a3;
    xr[(size_t)(node0 + 0) * 32 + f] = r0;
    xr[(size_t)(node0 + 1) * 32 + f] = r1;
    xr[(size_t)(node0 + 2) * 32 + f] = r2;
    xr[(size_t)(node0 + 3) * 32 + f] = r3;
}

// ---------------------------------------------------------------------------
// Counting sort by dst-bucket with single-writer (bucket, chunk) regions.
// ---------------------------------------------------------------------------
__global__ __launch_bounds__(256) void bkt_hist(const int* __restrict__ ei,
                                                int* __restrict__ cnt)
{
    __shared__ int hloc[NBK];
    for (int i = threadIdx.x; i < NBK; i += 256) hloc[i] = 0;
    __syncthreads();
    const int c  = blockIdx.x;
    const int e0 = c * CHUNK;
    for (int i = threadIdx.x; i < CHUNK; i += 256) {
        const int dst = __builtin_nontemporal_load(&ei[N_EDGES + e0 + i]);
        atomicAdd(&hloc[dst / BNK], 1);
    }
    __syncthreads();
    for (int b = threadIdx.x; b < NBK; b += 256)
        cnt[b * HG + c] = hloc[b];
}

__global__ __launch_bounds__(256) void scan_tot(const int* __restrict__ cnt,
                                                int* __restrict__ tot)
{
    const int b = blockIdx.x * 256 + threadIdx.x;
    const int* row = cnt + (size_t)b * HG;
    int s = 0;
#pragma unroll 8
    for (int i = 0; i < HG; ++i) s += row[i];
    tot[b] = s;
}

__global__ __launch_bounds__(1024) void scan_excl(const int* __restrict__ tot,
                                                  int* __restrict__ bbase)
{
    __shared__ int s[1024];
    const int t = threadIdx.x;
    const int t0 = tot[4 * t], t1 = tot[4 * t + 1], t2 = tot[4 * t + 2], t3 = tot[4 * t + 3];
    const int sum = t0 + t1 + t2 + t3;
    s[t] = sum;
    __syncthreads();
    for (int off = 1; off < 1024; off <<= 1) {
        const int u = (t >= off) ? s[t - off] : 0;
        __syncthreads();
        s[t] += u;
        __syncthreads();
    }
    int run = s[t] - sum;
    bbase[4 * t]     = run; run += t0;
    bbase[4 * t + 1] = run; run += t1;
    bbase[4 * t + 2] = run; run += t2;
    bbase[4 * t + 3] = run;
}

__global__ __launch_bounds__(256) void scan_write(const int* __restrict__ cnt,
                                                  const int* __restrict__ bbase,
                                                  int* __restrict__ base)
{
    const int b = blockIdx.x * 256 + threadIdx.x;
    const int* row = cnt + (size_t)b * HG;
    int* brow = base + (size_t)b * HG;
    int run = bbase[b];
#pragma unroll 8
    for (int i = 0; i < HG; ++i) { brow[i] = run; run += row[i]; }
    if (b == NBK - 1) base[NCUR] = run;   // == N_EDGES
}

__global__ __launch_bounds__(256) void bkt_scatter(const int* __restrict__ ei,
                                                   const float* __restrict__ eattr,
                                                   const int* __restrict__ base,
                                                   int2* __restrict__ es2)
{
    __shared__ int cur[NBK];
    const int c = blockIdx.x;
    for (int b = threadIdx.x; b < NBK; b += 256) cur[b] = base[b * HG + c];
    __syncthreads();
    const int e0 = c * CHUNK;
    for (int i = threadIdx.x; i < CHUNK; i += 256) {
        const int e   = e0 + i;
        const int src = __builtin_nontemporal_load(&ei[e]);
        const int dst = __builtin_nontemporal_load(&ei[N_EDGES + e]);
        const float ea = __builtin_nontemporal_load(&eattr[e]);
        const int b  = dst / BNK;
        const int dl = dst - b * BNK;          // 0..24 (5 bits); src < 2^17
        const int pos = atomicAdd(&cur[b], 1);
        const long long raw = (long long)(unsigned)(src | (dl << 17))
                            | ((long long)__float_as_int(ea) << 32);
        __builtin_nontemporal_store(raw, (long long*)&es2[pos]);
    }
}

// ---------------------------------------------------------------------------
// Fused logit + softmax-weight + aggregate. One xl gather per edge TOTAL.
// Block per bucket (25 dst nodes); xr staged in LDS (PAD=36: conflict-free);
// group-per-edge, contiguous per-group chunks, 4-edge ILP batches;
// ds_add_f32 LDS accumulation. h output overwrites xr buffer.
// ---------------------------------------------------------------------------
#define PROC(w, eaI, xv) do {                                                 \
    const int dl_ = (w) >> 17;                                                \
    float m_ = (xv) + sxr[dl_ * PAD + f] + __int_as_float((int)(eaI)) * wef;  \
    m_ = (m_ > 0.f) ? m_ : 0.2f * m_;                                         \
    float t_ = m_ * attf;                                                     \
    t_ += __shfl_xor(t_, 16, 32);                                             \
    t_ += __shfl_xor(t_, 8, 32);                                              \
    t_ += __shfl_xor(t_, 4, 32);                                              \
    t_ += __shfl_xor(t_, 2, 32);                                              \
    t_ += __shfl_xor(t_, 1, 32);                                              \
    const float p_ = __expf(t_);                                              \
    unsafeAtomicAdd(&sacc[dl_ * PAD + f], (xv) * p_);                         \
    if (f == 0) unsafeAtomicAdd(&sden[dl_], p_);                              \
} while (0)

__global__ __launch_bounds__(256) void gat_fused(
    const int2* __restrict__ es2, const int* __restrict__ base,
    const float* __restrict__ We, const float* __restrict__ att,
    const float* __restrict__ xl, float* xrh)
{
    __shared__ float sxr[BNK * PAD];
    __shared__ float sacc[BNK * PAD];
    __shared__ float sden[BNK];

    const int b    = blockIdx.x;
    const int n0   = b * BNK;
    const int nrow = (N_NODES - n0 < BNK) ? (N_NODES - n0) : BNK;
    const int tid  = threadIdx.x;

    if (nrow > 0) {
        for (int i = tid; i < nrow * 32; i += 256) {
            const int r = i >> 5, cc = i & 31;
            sxr[r * PAD + cc]  = xrh[(size_t)(n0 + r) * 32 + cc];
            sacc[r * PAD + cc] = 0.f;
        }
        for (int i = tid; i < nrow; i += 256) sden[i] = 0.f;
    }
    __syncthreads();
    if (nrow <= 0) return;

    const int f = tid & 31;
    const int g = tid >> 5;
    const float attf = att[f];
    const float wef  = We[f];

    const int beg   = base[b * HG];
    const int end   = base[(b + 1) * HG];
    const int L     = (end - beg + 7) >> 3;
    int j  = beg + g * L;
    int jE = j + L; if (jE > end) jE = end;

    const long long* es8 = (const long long*)es2;

    for (; j + 4 <= jE; j += 4) {
        const long long r0 = __builtin_nontemporal_load(&es8[j]);
        const long long r1 = __builtin_nontemporal_load(&es8[j + 1]);
        const long long r2 = __builtin_nontemporal_load(&es8[j + 2]);
        const long long r3 = __builtin_nontemporal_load(&es8[j + 3]);
        const int w0 = (int)r0, w1 = (int)r1, w2 = (int)r2, w3 = (int)r3;
        const float x0 = xl[(size_t)(w0 & 0x1FFFF) * 32 + f];
        const float x1 = xl[(size_t)(w1 & 0x1FFFF) * 32 + f];
        const float x2 = xl[(size_t)(w2 & 0x1FFFF) * 32 + f];
        const float x3 = xl[(size_t)(w3 & 0x1FFFF) * 32 + f];
        PROC(w0, r0 >> 32, x0);
        PROC(w1, r1 >> 32, x1);
        PROC(w2, r2 >> 32, x2);
        PROC(w3, r3 >> 32, x3);
    }
    for (; j < jE; ++j) {
        const long long r0 = __builtin_nontemporal_load(&es8[j]);
        const int w0 = (int)r0;
        const float x0 = xl[(size_t)(w0 & 0x1FFFF) * 32 + f];
        PROC(w0, r0 >> 32, x0);
    }
    __syncthreads();

    for (int i = tid; i < nrow * 32; i += 256) {
        const int r = i >> 5, cc = i & 31;
        xrh[(size_t)(n0 + r) * 32 + cc] = sacc[r * PAD + cc] / (sden[r] + 1e-16f);
    }
}

// ---------------------------------------------------------------------------
// Pool: mean over each graph's node range (batch sorted), + bias.
// ---------------------------------------------------------------------------
__global__ __launch_bounds__(256) void gat_pool(
    const float* __restrict__ h, const float* __restrict__ bias,
    const int* __restrict__ batch, float* __restrict__ out)
{
    const int g = blockIdx.x;
    __shared__ int s_lo, s_hi;
    if (threadIdx.x == 0) {
        int lo = 0, hi = N_NODES;
        while (lo < hi) { int mid = (lo + hi) >> 1; if (batch[mid] < g) lo = mid + 1; else hi = mid; }
        s_lo = lo;
        lo = 0; hi = N_NODES;
        while (lo < hi) { int mid = (lo + hi) >> 1; if (batch[mid] < g + 1) lo = mid + 1; else hi = mid; }
        s_hi = lo;
    }
    __syncthreads();
    const int lo = s_lo, hi = s_hi;

    const int f   = threadIdx.x & 31;
    const int grp = threadIdx.x >> 5;

    float acc = 0.f;
    for (int n = lo + grp; n < hi; n += 8)
        acc += h[(size_t)n * 32 + f];

    __shared__ float s_acc[8][32];
    s_acc[grp][f] = acc;
    __syncthreads();

    if (threadIdx.x < 32) {
        float sum = 0.f;
#pragma unroll
        for (int i = 0; i < 8; ++i) sum += s_acc[i][f];
        const int cnt = hi - lo;
        out[g * 32 + f] = (cnt > 0) ? (sum / (float)cnt + bias[f]) : 0.f;
    }
}

// ---------------------------------------------------------------------------
extern "C" void kernel_launch(void* const* d_in, const int* in_sizes, int n_in,
                              void* d_out, int out_size, void* d_ws, size_t ws_size,
                              hipStream_t stream)
{
    const float* x     = (const float*)d_in[0];
    const float* eattr = (const float*)d_in[1];
    const float* Wl    = (const float*)d_in[2];
    const float* bl    = (const float*)d_in[3];
    const float* Wr    = (const float*)d_in[4];
    const float* br    = (const float*)d_in[5];
    const float* We    = (const float*)d_in[6];
    const float* att   = (const float*)d_in[7];
    const float* bias  = (const float*)d_in[8];
    const int*   ei    = (const int*)d_in[9];
    const int*   batch = (const int*)d_in[10];
    float* out = (float*)d_out;

    float* ws = (float*)d_ws;
    const size_t NF = (size_t)N_NODES * 32;

    float* xl    = ws;                        // [NF]
    float* xrh   = ws + NF;                   // [NF]   xr, then h
    int2*  es2   = (int2*)(ws + 2 * NF);      // [N_EDGES]
    int*   cnt   = (int*)(es2 + N_EDGES);     // [NCUR]
    int*   base  = cnt + NCUR;                // [NCUR + 1]
    int*   tot   = base + NCUR + 1;           // [NBK]
    int*   bbase = tot + NBK;                 // [NBK]

    gat_transform<<<N_NODES / 32, 256, 0, stream>>>(x, Wl, bl, Wr, br, xl, xrh);
    bkt_hist<<<HG, 256, 0, stream>>>(ei, cnt);
    scan_tot<<<NBK / 256, 256, 0, stream>>>(cnt, tot);
    scan_excl<<<1, 1024, 0, stream>>>(tot, bbase);
    scan_write<<<NBK / 256, 256, 0, stream>>>(cnt, bbase, base);
    bkt_scatter<<<HG, 256, 0, stream>>>(ei, eattr, base, es2);
    gat_fused<<<NBK, 256, 0, stream>>>(es2, base, We, att, xl, xrh);
    gat_pool<<<N_GRAPHS, 256, 0, stream>>>(xrh, bias, batch, out);
}

// Round 7
// 865.102 us; speedup vs baseline: 1.2516x; 1.0944x over previous
//
#include <hip/hip_runtime.h>

#define N_NODES 100000
#define N_EDGES 3200000
#define F_IN 128
#define F_OUT 32
#define N_GRAPHS 64

#define NBK 4096                   // dst buckets
#define BNK 25                     // nodes/bucket: 4096*25 >= N
#define PAD 36                     // LDS row pad in floats (144B = 9*16 keeps float4 align)
#define HG  128                    // chunk blocks for hist/scatter
#define CHUNK (N_EDGES / HG)       // 25000, exact
#define NCUR (NBK * HG)            // 524288 cursors

// DPP ctrl encodings (gfx9+)
#define DPP_QUAD_XOR1 0xB1         // quad_perm(1,0,3,2)
#define DPP_QUAD_XOR2 0x4E         // quad_perm(2,3,0,1)
#define DPP_HALF_MIRROR 0x141      // row_half_mirror: lane ^ 7 within 8

template <int CTRL>
__device__ __forceinline__ float dpp_add(float v) {
    return v + __int_as_float(__builtin_amdgcn_update_dpp(
        0, __float_as_int(v), CTRL, 0xF, 0xF, true));
}

// ---------------------------------------------------------------------------
// Transform: xl = x@W_l + b_l ; xr = x@W_r + b_r. 4 nodes per 32-lane group.
// ---------------------------------------------------------------------------
__global__ __launch_bounds__(256) void gat_transform(
    const float* __restrict__ x,
    const float* __restrict__ Wl, const float* __restrict__ bl,
    const float* __restrict__ Wr, const float* __restrict__ br,
    float* __restrict__ xl, float* __restrict__ xr)
{
    __shared__ float2 sW[F_IN * F_OUT];
    for (int i = threadIdx.x; i < F_IN * F_OUT; i += 256)
        sW[i] = make_float2(Wl[i], Wr[i]);
    __syncthreads();

    const int f     = threadIdx.x & 31;
    const int node0 = blockIdx.x * 32 + (threadIdx.x >> 5) * 4;

    const float4* x0 = (const float4*)(x + (size_t)(node0 + 0) * F_IN);
    const float4* x1 = (const float4*)(x + (size_t)(node0 + 1) * F_IN);
    const float4* x2 = (const float4*)(x + (size_t)(node0 + 2) * F_IN);
    const float4* x3 = (const float4*)(x + (size_t)(node0 + 3) * F_IN);

    const float bl_f = bl[f], br_f = br[f];
    float a0 = bl_f, a1 = bl_f, a2 = bl_f, a3 = bl_f;
    float r0 = br_f, r1 = br_f, r2 = br_f, r3 = br_f;

#pragma unroll 4
    for (int k4 = 0; k4 < F_IN / 4; ++k4) {
        float4 v0 = x0[k4], v1 = x1[k4], v2 = x2[k4], v3 = x3[k4];
        float2 w0 = sW[(4 * k4 + 0) * 32 + f];
        float2 w1 = sW[(4 * k4 + 1) * 32 + f];
        float2 w2 = sW[(4 * k4 + 2) * 32 + f];
        float2 w3 = sW[(4 * k4 + 3) * 32 + f];
        a0 += v0.x * w0.x + v0.y * w1.x + v0.z * w2.x + v0.w * w3.x;
        r0 += v0.x * w0.y + v0.y * w1.y + v0.z * w2.y + v0.w * w3.y;
        a1 += v1.x * w0.x + v1.y * w1.x + v1.z * w2.x + v1.w * w3.x;
        r1 += v1.x * w0.y + v1.y * w1.y + v1.z * w2.y + v1.w * w3.y;
        a2 += v2.x * w0.x + v2.y * w1.x + v2.z * w2.x + v2.w * w3.x;
        r2 += v2.x * w0.y + v2.y * w1.y + v2.z * w2.y + v2.w * w3.y;
        a3 += v3.x * w0.x + v3.y * w1.x + v3.z * w2.x + v3.w * w3.x;
        r3 += v3.x * w0.y + v3.y * w1.y + v3.z * w2.y + v3.w * w3.y;
    }
    xl[(size_t)(node0 + 0) * 32 + f] = a0;
    xl[(size_t)(node0 + 1) * 32 + f] = a1;
    xl[(size_t)(node0 + 2) * 32 + f] = a2;
    xl[(size_t)(node0 + 3) * 32 + f] = a3;
    xr[(size_t)(node0 + 0) * 32 + f] = r0;
    xr[(size_t)(node0 + 1) * 32 + f] = r1;
    xr[(size_t)(node0 + 2) * 32 + f] = r2;
    xr[(size_t)(node0 + 3) * 32 + f] = r3;
}

// ---------------------------------------------------------------------------
// Counting sort by dst-bucket with single-writer (bucket, chunk) regions.
// ---------------------------------------------------------------------------
__global__ __launch_bounds__(256) void bkt_hist(const int* __restrict__ ei,
                                                int* __restrict__ cnt)
{
    __shared__ int hloc[NBK];
    for (int i = threadIdx.x; i < NBK; i += 256) hloc[i] = 0;
    __syncthreads();
    const int c  = blockIdx.x;
    const int e0 = c * CHUNK;
    for (int i = threadIdx.x; i < CHUNK; i += 256) {
        const int dst = __builtin_nontemporal_load(&ei[N_EDGES + e0 + i]);
        atomicAdd(&hloc[dst / BNK], 1);
    }
    __syncthreads();
    for (int b = threadIdx.x; b < NBK; b += 256)
        cnt[b * HG + c] = hloc[b];
}

__global__ __launch_bounds__(256) void scan_tot(const int* __restrict__ cnt,
                                                int* __restrict__ tot)
{
    const int b = blockIdx.x * 256 + threadIdx.x;
    const int* row = cnt + (size_t)b * HG;
    int s = 0;
#pragma unroll 8
    for (int i = 0; i < HG; ++i) s += row[i];
    tot[b] = s;
}

__global__ __launch_bounds__(1024) void scan_excl(const int* __restrict__ tot,
                                                  int* __restrict__ bbase)
{
    __shared__ int s[1024];
    const int t = threadIdx.x;
    const int t0 = tot[4 * t], t1 = tot[4 * t + 1], t2 = tot[4 * t + 2], t3 = tot[4 * t + 3];
    const int sum = t0 + t1 + t2 + t3;
    s[t] = sum;
    __syncthreads();
    for (int off = 1; off < 1024; off <<= 1) {
        const int u = (t >= off) ? s[t - off] : 0;
        __syncthreads();
        s[t] += u;
        __syncthreads();
    }
    int run = s[t] - sum;
    bbase[4 * t]     = run; run += t0;
    bbase[4 * t + 1] = run; run += t1;
    bbase[4 * t + 2] = run; run += t2;
    bbase[4 * t + 3] = run;
}

__global__ __launch_bounds__(256) void scan_write(const int* __restrict__ cnt,
                                                  const int* __restrict__ bbase,
                                                  int* __restrict__ base)
{
    const int b = blockIdx.x * 256 + threadIdx.x;
    const int* row = cnt + (size_t)b * HG;
    int* brow = base + (size_t)b * HG;
    int run = bbase[b];
#pragma unroll 8
    for (int i = 0; i < HG; ++i) { brow[i] = run; run += row[i]; }
    if (b == NBK - 1) base[NCUR] = run;   // == N_EDGES
}

__global__ __launch_bounds__(256) void bkt_scatter(const int* __restrict__ ei,
                                                   const float* __restrict__ eattr,
                                                   const int* __restrict__ base,
                                                   int2* __restrict__ es2)
{
    __shared__ int cur[NBK];
    const int c = blockIdx.x;
    for (int b = threadIdx.x; b < NBK; b += 256) cur[b] = base[b * HG + c];
    __syncthreads();
    const int e0 = c * CHUNK;
    for (int i = threadIdx.x; i < CHUNK; i += 256) {
        const int e   = e0 + i;
        const int src = __builtin_nontemporal_load(&ei[e]);
        const int dst = __builtin_nontemporal_load(&ei[N_EDGES + e]);
        const float ea = __builtin_nontemporal_load(&eattr[e]);
        const int b  = dst / BNK;
        const int dl = dst - b * BNK;          // 0..24 (5 bits); src < 2^17
        const int pos = atomicAdd(&cur[b], 1);
        const long long raw = (long long)(unsigned)(src | (dl << 17))
                            | ((long long)__float_as_int(ea) << 32);
        __builtin_nontemporal_store(raw, (long long*)&es2[pos]);
    }
}

// ---------------------------------------------------------------------------
// Fused logit + softmax-weight + aggregate. 8 LANES PER EDGE (float4/lane):
// one dwordx4 gather instr = 8 edges = 16 lines in flight. Reduce via 3 DPP
// v_add (no DS round-trips). xr from global (25 rows/block -> L1-resident).
// LDS holds only sacc/sden; ds_add_f32 fire-and-forget accumulation.
// ---------------------------------------------------------------------------
__global__ __launch_bounds__(256, 8) void gat_fused(
    const int2* __restrict__ es2, const int* __restrict__ base,
    const float* __restrict__ We, const float* __restrict__ att,
    const float* __restrict__ xl, float* xrh)
{
    __shared__ float sacc[BNK * PAD];
    __shared__ float sden[BNK];

    const int b    = blockIdx.x;
    const int n0   = b * BNK;
    const int nrow = (N_NODES - n0 < BNK) ? (N_NODES - n0) : BNK;
    if (nrow <= 0) return;                     // uniform over block
    const int tid = threadIdx.x;

    for (int i = tid; i < BNK * PAD; i += 256) sacc[i] = 0.f;
    for (int i = tid; i < BNK; i += 256)       sden[i] = 0.f;
    __syncthreads();

    const int lane  = tid & 63;
    const int wave  = tid >> 6;                // 0..3
    const int sub   = lane & 7;                // float4 slot within edge
    const int eslot = lane >> 3;               // 0..7: edge within batch

    const float4 we4 = ((const float4*)We)[sub];
    const float4 at4 = ((const float4*)att)[sub];

    const int beg = base[b * HG];
    const int end = base[(b + 1) * HG];
    const int L   = (end - beg + 3) >> 2;      // per-wave chunk
    const int wbeg = beg + wave * L;
    int wend = wbeg + L; if (wend > end) wend = end;

    const long long* es8 = (const long long*)es2;
    const float4* xl4 = (const float4*)xl;
    const float4* xr4 = (const float4*)xrh;

    for (int j = wbeg; j < wend; j += 8) {
        const int  jj    = j + eslot;
        const bool valid = (jj < wend);
        const int  jc    = valid ? jj : (wend - 1);

        const long long r = __builtin_nontemporal_load(&es8[jc]);
        const int  w   = (int)r;
        const int  src = w & 0x1FFFF;
        const int  dl  = w >> 17;
        const float ea = __int_as_float((int)(r >> 32));

        const float4 xlv = xl4[(size_t)src * 8 + sub];            // random gather
        const float4 xrv = xr4[(size_t)(n0 + dl) * 8 + sub];      // L1-resident

        float m, s = 0.f;
        m = xlv.x + xrv.x + ea * we4.x; m = (m > 0.f) ? m : 0.2f * m; s += m * at4.x;
        m = xlv.y + xrv.y + ea * we4.y; m = (m > 0.f) ? m : 0.2f * m; s += m * at4.y;
        m = xlv.z + xrv.z + ea * we4.z; m = (m > 0.f) ? m : 0.2f * m; s += m * at4.z;
        m = xlv.w + xrv.w + ea * we4.w; m = (m > 0.f) ? m : 0.2f * m; s += m * at4.w;

        // 8-lane reduce, pure VALU: quad sums then cross-quad pair
        s = dpp_add<DPP_QUAD_XOR1>(s);
        s = dpp_add<DPP_QUAD_XOR2>(s);
        s = dpp_add<DPP_HALF_MIRROR>(s);

        const float p = __expf(s) * (valid ? 1.f : 0.f);

        float* srow = &sacc[dl * PAD + sub * 4];
        unsafeAtomicAdd(&srow[0], xlv.x * p);
        unsafeAtomicAdd(&srow[1], xlv.y * p);
        unsafeAtomicAdd(&srow[2], xlv.z * p);
        unsafeAtomicAdd(&srow[3], xlv.w * p);
        if (sub == 0) unsafeAtomicAdd(&sden[dl], p);
    }
    __syncthreads();

    for (int i = tid; i < nrow * 32; i += 256) {
        const int r = i >> 5, cc = i & 31;
        xrh[(size_t)(n0 + r) * 32 + cc] = sacc[r * PAD + cc] / (sden[r] + 1e-16f);
    }
}

// ---------------------------------------------------------------------------
// Pool: mean over each graph's node range (batch sorted), + bias.
// ---------------------------------------------------------------------------
__global__ __launch_bounds__(256) void gat_pool(
    const float* __restrict__ h, const float* __restrict__ bias,
    const int* __restrict__ batch, float* __restrict__ out)
{
    const int g = blockIdx.x;
    __shared__ int s_lo, s_hi;
    if (threadIdx.x == 0) {
        int lo = 0, hi = N_NODES;
        while (lo < hi) { int mid = (lo + hi) >> 1; if (batch[mid] < g) lo = mid + 1; else hi = mid; }
        s_lo = lo;
        lo = 0; hi = N_NODES;
        while (lo < hi) { int mid = (lo + hi) >> 1; if (batch[mid] < g + 1) lo = mid + 1; else hi = mid; }
        s_hi = lo;
    }
    __syncthreads();
    const int lo = s_lo, hi = s_hi;

    const int f   = threadIdx.x & 31;
    const int grp = threadIdx.x >> 5;

    float acc = 0.f;
    for (int n = lo + grp; n < hi; n += 8)
        acc += h[(size_t)n * 32 + f];

    __shared__ float s_acc[8][32];
    s_acc[grp][f] = acc;
    __syncthreads();

    if (threadIdx.x < 32) {
        float sum = 0.f;
#pragma unroll
        for (int i = 0; i < 8; ++i) sum += s_acc[i][f];
        const int cnt = hi - lo;
        out[g * 32 + f] = (cnt > 0) ? (sum / (float)cnt + bias[f]) : 0.f;
    }
}

// ---------------------------------------------------------------------------
extern "C" void kernel_launch(void* const* d_in, const int* in_sizes, int n_in,
                              void* d_out, int out_size, void* d_ws, size_t ws_size,
                              hipStream_t stream)
{
    const float* x     = (const float*)d_in[0];
    const float* eattr = (const float*)d_in[1];
    const float* Wl    = (const float*)d_in[2];
    const float* bl    = (const float*)d_in[3];
    const float* Wr    = (const float*)d_in[4];
    const float* br    = (const float*)d_in[5];
    const float* We    = (const float*)d_in[6];
    const float* att   = (const float*)d_in[7];
    const float* bias  = (const float*)d_in[8];
    const int*   ei    = (const int*)d_in[9];
    const int*   batch = (const int*)d_in[10];
    float* out = (float*)d_out;

    float* ws = (float*)d_ws;
    const size_t NF = (size_t)N_NODES * 32;

    float* xl    = ws;                        // [NF]
    float* xrh   = ws + NF;                   // [NF]   xr, then h
    int2*  es2   = (int2*)(ws + 2 * NF);      // [N_EDGES]
    int*   cnt   = (int*)(es2 + N_EDGES);     // [NCUR]
    int*   base  = cnt + NCUR;                // [NCUR + 1]
    int*   tot   = base + NCUR + 1;           // [NBK]
    int*   bbase = tot + NBK;                 // [NBK]

    gat_transform<<<N_NODES / 32, 256, 0, stream>>>(x, Wl, bl, Wr, br, xl, xrh);
    bkt_hist<<<HG, 256, 0, stream>>>(ei, cnt);
    scan_tot<<<NBK / 256, 256, 0, stream>>>(cnt, tot);
    scan_excl<<<1, 1024, 0, stream>>>(tot, bbase);
    scan_write<<<NBK / 256, 256, 0, stream>>>(cnt, bbase, base);
    bkt_scatter<<<HG, 256, 0, stream>>>(ei, eattr, base, es2);
    gat_fused<<<NBK, 256, 0, stream>>>(es2, base, We, att, xl, xrh);
    gat_pool<<<N_GRAPHS, 256, 0, stream>>>(xrh, bias, batch, out);
}

// Round 8
// 635.821 us; speedup vs baseline: 1.7030x; 1.3606x over previous
//
#include <hip/hip_runtime.h>
#include <hip/hip_fp16.h>

#define N_NODES 100000
#define N_EDGES 3200000
#define F_IN 128
#define F_OUT 32
#define N_GRAPHS 64

#define UNROLL 4

// DPP ctrl encodings (gfx9+)
#define DPP_QUAD_XOR1   0xB1   // quad_perm(1,0,3,2)
#define DPP_QUAD_XOR2   0x4E   // quad_perm(2,3,0,1)
#define DPP_HALF_MIRROR 0x141  // lane ^ 7 within 8
#define DPP_ROW_MIRROR  0x140  // lane -> 15-lane within 16

template <int CTRL>
__device__ __forceinline__ float dpp_add(float v) {
    return v + __int_as_float(__builtin_amdgcn_update_dpp(
        0, __float_as_int(v), CTRL, 0xF, 0xF, true));
}

// ---------------------------------------------------------------------------
// Transform: xl = x@W_l + b_l ; xr = x@W_r + b_r, stored as fp16 rows (64B).
// 4 nodes per 32-lane group; W staged in LDS as float2.
// ---------------------------------------------------------------------------
__global__ __launch_bounds__(256) void gat_transform(
    const float* __restrict__ x,
    const float* __restrict__ Wl, const float* __restrict__ bl,
    const float* __restrict__ Wr, const float* __restrict__ br,
    __half* __restrict__ xl16, __half* __restrict__ xr16)
{
    __shared__ float2 sW[F_IN * F_OUT];
    for (int i = threadIdx.x; i < F_IN * F_OUT; i += 256)
        sW[i] = make_float2(Wl[i], Wr[i]);
    __syncthreads();

    const int f     = threadIdx.x & 31;
    const int node0 = blockIdx.x * 32 + (threadIdx.x >> 5) * 4;

    const float4* x0 = (const float4*)(x + (size_t)(node0 + 0) * F_IN);
    const float4* x1 = (const float4*)(x + (size_t)(node0 + 1) * F_IN);
    const float4* x2 = (const float4*)(x + (size_t)(node0 + 2) * F_IN);
    const float4* x3 = (const float4*)(x + (size_t)(node0 + 3) * F_IN);

    const float bl_f = bl[f], br_f = br[f];
    float a0 = bl_f, a1 = bl_f, a2 = bl_f, a3 = bl_f;
    float r0 = br_f, r1 = br_f, r2 = br_f, r3 = br_f;

#pragma unroll 4
    for (int k4 = 0; k4 < F_IN / 4; ++k4) {
        float4 v0 = x0[k4], v1 = x1[k4], v2 = x2[k4], v3 = x3[k4];
        float2 w0 = sW[(4 * k4 + 0) * 32 + f];
        float2 w1 = sW[(4 * k4 + 1) * 32 + f];
        float2 w2 = sW[(4 * k4 + 2) * 32 + f];
        float2 w3 = sW[(4 * k4 + 3) * 32 + f];
        a0 += v0.x * w0.x + v0.y * w1.x + v0.z * w2.x + v0.w * w3.x;
        r0 += v0.x * w0.y + v0.y * w1.y + v0.z * w2.y + v0.w * w3.y;
        a1 += v1.x * w0.x + v1.y * w1.x + v1.z * w2.x + v1.w * w3.x;
        r1 += v1.x * w0.y + v1.y * w1.y + v1.z * w2.y + v1.w * w3.y;
        a2 += v2.x * w0.x + v2.y * w1.x + v2.z * w2.x + v2.w * w3.x;
        r2 += v2.x * w0.y + v2.y * w1.y + v2.z * w2.y + v2.w * w3.y;
        a3 += v3.x * w0.x + v3.y * w1.x + v3.z * w2.x + v3.w * w3.x;
        r3 += v3.x * w0.y + v3.y * w1.y + v3.z * w2.y + v3.w * w3.y;
    }
    xl16[(size_t)(node0 + 0) * 32 + f] = __float2half_rn(a0);
    xl16[(size_t)(node0 + 1) * 32 + f] = __float2half_rn(a1);
    xl16[(size_t)(node0 + 2) * 32 + f] = __float2half_rn(a2);
    xl16[(size_t)(node0 + 3) * 32 + f] = __float2half_rn(a3);
    xr16[(size_t)(node0 + 0) * 32 + f] = __float2half_rn(r0);
    xr16[(size_t)(node0 + 1) * 32 + f] = __float2half_rn(r1);
    xr16[(size_t)(node0 + 2) * 32 + f] = __float2half_rn(r2);
    xr16[(size_t)(node0 + 3) * 32 + f] = __float2half_rn(r3);
}

// ---------------------------------------------------------------------------
// Edge pass (R1 skeleton): 32-lane group per edge, 4-edge ILP.
// fp16 row gathers (1 line each), reduce = 4 DPP adds + 1 shfl_xor(16),
// native fire-and-forget f32 atomics (no CAS read-back).
// exp without max-subtraction (cancels in softmax; logits ~N(0,1.3), safe).
// ---------------------------------------------------------------------------
__global__ __launch_bounds__(256) void gat_edge16(
    const int* __restrict__ ei, const float* __restrict__ eattr,
    const float* __restrict__ We, const float* __restrict__ att,
    const __half* __restrict__ xl16, const __half* __restrict__ xr16,
    float* __restrict__ outacc, float* __restrict__ denom)
{
    const int f = threadIdx.x & 31;
    const float attf = att[f];
    const float wef  = We[f];
    const int group = (blockIdx.x * blockDim.x + threadIdx.x) >> 5;
    const int ng    = (gridDim.x * blockDim.x) >> 5;

    for (int e0 = group; e0 < N_EDGES; e0 += UNROLL * ng) {
        int  eIdx[UNROLL];
        bool val[UNROLL];
        int  src[UNROLL], dst[UNROLL];
        float ea[UNROLL], xlv[UNROLL], xrv[UNROLL];

#pragma unroll
        for (int u = 0; u < UNROLL; ++u) {
            const int e = e0 + u * ng;
            val[u]  = (e < N_EDGES);
            eIdx[u] = val[u] ? e : e0;
        }
#pragma unroll
        for (int u = 0; u < UNROLL; ++u) {
            src[u] = ei[eIdx[u]];
            dst[u] = ei[N_EDGES + eIdx[u]];
            ea[u]  = eattr[eIdx[u]];
        }
#pragma unroll
        for (int u = 0; u < UNROLL; ++u) {
            xlv[u] = __half2float(xl16[(size_t)src[u] * 32 + f]);
            xrv[u] = __half2float(xr16[(size_t)dst[u] * 32 + f]);
        }
#pragma unroll
        for (int u = 0; u < UNROLL; ++u) {
            float m = xlv[u] + xrv[u] + ea[u] * wef;
            m = (m > 0.f) ? m : 0.2f * m;
            float t = m * attf;
            t = dpp_add<DPP_QUAD_XOR1>(t);    // 2-lane sums
            t = dpp_add<DPP_QUAD_XOR2>(t);    // 4-lane sums
            t = dpp_add<DPP_HALF_MIRROR>(t);  // 8-lane sums
            t = dpp_add<DPP_ROW_MIRROR>(t);   // 16-lane sums
            t += __shfl_xor(t, 16, 32);       // 32-lane sum, broadcast
            const float p = __expf(t);
            if (val[u]) {
                unsafeAtomicAdd(&outacc[(size_t)dst[u] * 32 + f], xlv[u] * p);
                if (f == 0) unsafeAtomicAdd(&denom[dst[u]], p);
            }
        }
    }
}

// ---------------------------------------------------------------------------
// Pool: normalize by denom, add bias, mean over each graph's node range.
// ---------------------------------------------------------------------------
__global__ __launch_bounds__(256) void gat_pool_div(
    const float* __restrict__ outacc, const float* __restrict__ denom,
    const float* __restrict__ bias, const int* __restrict__ batch,
    float* __restrict__ out)
{
    const int g = blockIdx.x;
    __shared__ int s_lo, s_hi;
    if (threadIdx.x == 0) {
        int lo = 0, hi = N_NODES;
        while (lo < hi) { int mid = (lo + hi) >> 1; if (batch[mid] < g) lo = mid + 1; else hi = mid; }
        s_lo = lo;
        lo = 0; hi = N_NODES;
        while (lo < hi) { int mid = (lo + hi) >> 1; if (batch[mid] < g + 1) lo = mid + 1; else hi = mid; }
        s_hi = lo;
    }
    __syncthreads();
    const int lo = s_lo, hi = s_hi;

    const int f   = threadIdx.x & 31;
    const int grp = threadIdx.x >> 5;

    float acc = 0.f;
    for (int n = lo + grp; n < hi; n += 8)
        acc += outacc[(size_t)n * 32 + f] / (denom[n] + 1e-16f);

    __shared__ float s_acc[8][32];
    s_acc[grp][f] = acc;
    __syncthreads();

    if (threadIdx.x < 32) {
        float sum = 0.f;
#pragma unroll
        for (int i = 0; i < 8; ++i) sum += s_acc[i][f];
        const int cnt = hi - lo;
        out[g * 32 + f] = (cnt > 0) ? (sum / (float)cnt + bias[f]) : 0.f;
    }
}

// ---------------------------------------------------------------------------
extern "C" void kernel_launch(void* const* d_in, const int* in_sizes, int n_in,
                              void* d_out, int out_size, void* d_ws, size_t ws_size,
                              hipStream_t stream)
{
    const float* x     = (const float*)d_in[0];
    const float* eattr = (const float*)d_in[1];
    const float* Wl    = (const float*)d_in[2];
    const float* bl    = (const float*)d_in[3];
    const float* Wr    = (const float*)d_in[4];
    const float* br    = (const float*)d_in[5];
    const float* We    = (const float*)d_in[6];
    const float* att   = (const float*)d_in[7];
    const float* bias  = (const float*)d_in[8];
    const int*   ei    = (const int*)d_in[9];
    const int*   batch = (const int*)d_in[10];
    float* out = (float*)d_out;

    const size_t NF = (size_t)N_NODES * 32;   // 3.2M elements

    __half* xl16   = (__half*)d_ws;
    __half* xr16   = xl16 + NF;
    float*  outacc = (float*)(xr16 + NF);
    float*  denom  = outacc + NF;

    // zero accumulators (outacc + denom contiguous)
    hipMemsetAsync(outacc, 0, (NF + N_NODES) * sizeof(float), stream);

    gat_transform<<<N_NODES / 32, 256, 0, stream>>>(x, Wl, bl, Wr, br, xl16, xr16);
    gat_edge16<<<4096, 256, 0, stream>>>(ei, eattr, We, att, xl16, xr16, outacc, denom);
    gat_pool_div<<<N_GRAPHS, 256, 0, stream>>>(outacc, denom, bias, batch, out);
}